// Round 1
// baseline (2343.622 us; speedup 1.0000x reference)
//
#include <hip/hip_runtime.h>
#include <hip/hip_bf16.h>

#define Bn  8
#define Cn  256
#define KCn 32
#define Nn  16384   // 128*128

__device__ __forceinline__ float elup1(float v) {
    // elu(v)+1 : v>0 ? v+1 : exp(v)
    return v > 0.0f ? v + 1.0f : __expf(v);
}

// ---------------------------------------------------------------------------
// Pass 1: km = elu(Wk x + bk)+1 per pixel (LDS only),
//         S[b][k][c] += sum_px x[c][px]*km[k][px],  Z[b][k] += sum_px km[k][px]
// grid (64 chunks, B), 256 thr. chunk = 256 pixels = 8 subtiles of 32.
// ---------------------------------------------------------------------------
__global__ __launch_bounds__(256) void k_km_S(const float* __restrict__ x,
                                              const float* __restrict__ Wk,
                                              const float* __restrict__ bk,
                                              float* __restrict__ S,
                                              float* __restrict__ Z) {
    __shared__ float xs[Cn][33];   // [c][p], pad -> conflict-free rows & cols
    __shared__ float km[KCn][36];  // [k][p], stride 36 -> 16B-aligned rows

    const int t  = threadIdx.x;
    const int b  = blockIdx.y;
    const int n0 = blockIdx.x * 256;
    const float* xb = x + (size_t)b * Cn * Nn;

    float Sacc[KCn];
#pragma unroll
    for (int k = 0; k < KCn; ++k) Sacc[k] = 0.f;
    float zacc = 0.f;

    const int pld = t & 31;          // staging: pixel
    const int cld = t >> 5;          // staging: channel offset (0..7)
    const int pk  = t & 31;          // km-compute: pixel
    const int kg  = (t >> 5) * 4;    // km-compute: 4 k-channels

    for (int sub = 0; sub < 8; ++sub) {
        const int ns = n0 + sub * 32;
        __syncthreads();             // protect xs/km from prev iter readers
        // ---- stage x subtile: 256ch x 32px ----
#pragma unroll
        for (int i = 0; i < 32; ++i) {
            const int c = i * 8 + cld;
            xs[c][pld] = xb[(size_t)c * Nn + ns + pld];
        }
        __syncthreads();
        // ---- km compute: thread = (pixel pk, k-channels kg..kg+3) ----
        float a0 = bk[kg + 0], a1 = bk[kg + 1], a2 = bk[kg + 2], a3 = bk[kg + 3];
#pragma unroll 8
        for (int c = 0; c < Cn; ++c) {
            const float xv = xs[c][pk];
            a0 += Wk[(kg + 0) * Cn + c] * xv;
            a1 += Wk[(kg + 1) * Cn + c] * xv;
            a2 += Wk[(kg + 2) * Cn + c] * xv;
            a3 += Wk[(kg + 3) * Cn + c] * xv;
        }
        km[kg + 0][pk] = elup1(a0);
        km[kg + 1][pk] = elup1(a1);
        km[kg + 2][pk] = elup1(a2);
        km[kg + 3][pk] = elup1(a3);
        __syncthreads();
        // ---- S accumulate: thread owns channel c = t ----
        float xv[32];
#pragma unroll
        for (int p = 0; p < 32; ++p) xv[p] = xs[t][p];
#pragma unroll
        for (int p4 = 0; p4 < 8; ++p4) {
#pragma unroll
            for (int k = 0; k < KCn; ++k) {
                const float4 k4 = *(const float4*)&km[k][p4 * 4];
                Sacc[k] += xv[p4 * 4 + 0] * k4.x + xv[p4 * 4 + 1] * k4.y
                         + xv[p4 * 4 + 2] * k4.z + xv[p4 * 4 + 3] * k4.w;
            }
        }
        // ---- z accumulate (one k-row per low thread) ----
        if (t < KCn) {
#pragma unroll
            for (int p = 0; p < 32; ++p) zacc += km[t][p];
        }
    }
    // ---- flush partials (coalesced atomics, S layout [b][k][c]) ----
    float* Sb = S + (size_t)b * KCn * Cn;
#pragma unroll
    for (int k = 0; k < KCn; ++k) atomicAdd(&Sb[k * Cn + t], Sacc[k]);
    if (t < KCn) atomicAdd(&Z[b * KCn + t], zacc);
}

// ---------------------------------------------------------------------------
// Pass 2 (tiny): KV[b][k][vc] = bv[vc]*Z[b][k] + sum_c Wv[vc][c] * S[b][k][c]
// stored bf16. grid (16 k-slices of 2, B), 256 thr (t = vc).
// ---------------------------------------------------------------------------
__global__ __launch_bounds__(256) void k_kv(const float* __restrict__ Wv,
                                            const float* __restrict__ bv,
                                            const float* __restrict__ S,
                                            const float* __restrict__ Z,
                                            __hip_bfloat16* __restrict__ KV) {
    __shared__ float Sl[2][Cn];
    const int t  = threadIdx.x;
    const int b  = blockIdx.y;
    const int k0 = blockIdx.x * 2;
    const float* Sb = S + ((size_t)b * KCn + k0) * Cn;
    Sl[0][t] = Sb[t];
    Sl[1][t] = Sb[Cn + t];
    __syncthreads();
    const float z0 = Z[b * KCn + k0], z1 = Z[b * KCn + k0 + 1];
    const float bvv = bv[t];
    float acc0 = bvv * z0, acc1 = bvv * z1;
    const float4* Wv4 = (const float4*)(Wv + (size_t)t * Cn);
#pragma unroll 8
    for (int c4 = 0; c4 < Cn / 4; ++c4) {
        const float4 w  = Wv4[c4];
        const float4 s0 = *(const float4*)&Sl[0][c4 * 4];
        const float4 s1 = *(const float4*)&Sl[1][c4 * 4];
        acc0 += w.x * s0.x + w.y * s0.y + w.z * s0.z + w.w * s0.w;
        acc1 += w.x * s1.x + w.y * s1.y + w.z * s1.z + w.w * s1.w;
    }
    KV[((size_t)b * KCn + k0 + 0) * Cn + t] = __float2bfloat16(acc0);
    KV[((size_t)b * KCn + k0 + 1) * Cn + t] = __float2bfloat16(acc1);
}

// ---------------------------------------------------------------------------
// Pass 3: per pixel qm = elu(Wq x + bq)+1; fold r = gamma/max(qz,1e-6) into qm;
//         out[b][vc][n] = sum_k qm'[k][n]*KV[k][vc] + x[b][vc][n]
// grid (64 chunks, B), 256 thr. q-phase: thread = pixel. out-phase: 4vc x 4px.
// ---------------------------------------------------------------------------
__global__ __launch_bounds__(256) void k_out(const float* __restrict__ x,
                                             const float* __restrict__ Wq,
                                             const float* __restrict__ bq,
                                             const __hip_bfloat16* __restrict__ KV,
                                             const float* __restrict__ Z,
                                             const float* __restrict__ gamma,
                                             float* __restrict__ out) {
    __shared__ float          qml[KCn][Cn];  // [k][pixel]  32 KB
    __shared__ __hip_bfloat16 kvl[KCn][Cn];  // [k][vc]     16 KB
    const int t  = threadIdx.x;
    const int b  = blockIdx.y;
    const int n0 = blockIdx.x * 256;
    const float* xb = x + (size_t)b * Cn * Nn;

    // ---- stage KV (8192 bf16, coalesced dword copies) ----
    {
        const unsigned int* src = (const unsigned int*)(KV + (size_t)b * KCn * Cn);
        unsigned int*       dst = (unsigned int*)&kvl[0][0];
#pragma unroll
        for (int i = 0; i < 16; ++i) dst[i * 256 + t] = src[i * 256 + t];
    }

    // ---- q phase: thread = pixel n0+t ----
    float qacc[KCn];
#pragma unroll
    for (int k = 0; k < KCn; ++k) qacc[k] = 0.f;
    const float* xp = xb + n0 + t;
#pragma unroll 4
    for (int c = 0; c < Cn; ++c) {
        const float xv = xp[(size_t)c * Nn];     // coalesced across lanes
        const float* wq = Wq + c;                // uniform -> scalar loads
#pragma unroll
        for (int k = 0; k < KCn; ++k) qacc[k] += wq[k * Cn] * xv;
    }
    float qz = 0.f;
#pragma unroll
    for (int k = 0; k < KCn; ++k) {
        qacc[k] = elup1(qacc[k] + bq[k]);
        qz += qacc[k] * Z[b * KCn + k];
    }
    const float r = gamma[0] / fmaxf(qz, 1e-6f);
#pragma unroll
    for (int k = 0; k < KCn; ++k) qml[k][t] = qacc[k] * r;
    __syncthreads();

    // ---- out phase: thread = (pixel-quad pq, vc-quad group vq) ----
    const int pq = t & 63;
    const int vq = t >> 6;
#pragma unroll 1
    for (int vs = 0; vs < 16; ++vs) {
        const int vc0 = vs * 16 + vq * 4;
        float a[4][4];
#pragma unroll
        for (int i = 0; i < 4; ++i)
#pragma unroll
            for (int j = 0; j < 4; ++j) a[i][j] = 0.f;
#pragma unroll
        for (int k = 0; k < KCn; ++k) {
            const float4  q4 = *(const float4*)&qml[k][pq * 4];       // b128
            const ushort4 kh = *(const ushort4*)&kvl[k][vc0];         // b64 bcast
            const float k0f = __uint_as_float((unsigned int)kh.x << 16);
            const float k1f = __uint_as_float((unsigned int)kh.y << 16);
            const float k2f = __uint_as_float((unsigned int)kh.z << 16);
            const float k3f = __uint_as_float((unsigned int)kh.w << 16);
            a[0][0] += k0f * q4.x; a[0][1] += k0f * q4.y; a[0][2] += k0f * q4.z; a[0][3] += k0f * q4.w;
            a[1][0] += k1f * q4.x; a[1][1] += k1f * q4.y; a[1][2] += k1f * q4.z; a[1][3] += k1f * q4.w;
            a[2][0] += k2f * q4.x; a[2][1] += k2f * q4.y; a[2][2] += k2f * q4.z; a[2][3] += k2f * q4.w;
            a[3][0] += k3f * q4.x; a[3][1] += k3f * q4.y; a[3][2] += k3f * q4.z; a[3][3] += k3f * q4.w;
        }
#pragma unroll
        for (int i = 0; i < 4; ++i) {
            const int vc = vc0 + i;
            const float4 xv4 = *(const float4*)(xb + (size_t)vc * Nn + n0 + pq * 4);
            float4 o;
            o.x = a[i][0] + xv4.x;
            o.y = a[i][1] + xv4.y;
            o.z = a[i][2] + xv4.z;
            o.w = a[i][3] + xv4.w;
            *(float4*)(out + ((size_t)b * Cn + vc) * Nn + n0 + pq * 4) = o;
        }
    }
}

// ---------------------------------------------------------------------------
extern "C" void kernel_launch(void* const* d_in, const int* in_sizes, int n_in,
                              void* d_out, int out_size, void* d_ws, size_t ws_size,
                              hipStream_t stream) {
    const float* x     = (const float*)d_in[0];
    const float* Wq    = (const float*)d_in[1];
    const float* bq    = (const float*)d_in[2];
    const float* Wk    = (const float*)d_in[3];
    const float* bk    = (const float*)d_in[4];
    const float* Wv    = (const float*)d_in[5];
    const float* bv    = (const float*)d_in[6];
    const float* gamma = (const float*)d_in[7];
    float* out = (float*)d_out;

    // workspace layout: S fp32 [B][KC][C] | Z fp32 [B][KC] | KV bf16 [B][KC][C]
    float* S = (float*)d_ws;
    float* Z = S + (size_t)Bn * KCn * Cn;
    __hip_bfloat16* KV = (__hip_bfloat16*)(Z + (size_t)Bn * KCn);

    hipMemsetAsync(d_ws, 0, ((size_t)Bn * KCn * Cn + Bn * KCn) * sizeof(float), stream);
    k_km_S<<<dim3(64, Bn), 256, 0, stream>>>(x, Wk, bk, S, Z);
    k_kv  <<<dim3(16, Bn), 256, 0, stream>>>(Wv, bv, S, Z, KV);
    k_out <<<dim3(64, Bn), 256, 0, stream>>>(x, Wq, bq, KV, Z, gamma, out);
}

// Round 2
// 693.911 us; speedup vs baseline: 3.3774x; 3.3774x over previous
//
#include <hip/hip_runtime.h>
#include <hip/hip_bf16.h>

#define Bn  8
#define Cn  256
#define KCn 32
#define Nn  16384   // 128*128

__device__ __forceinline__ float elup1(float v) {
    // elu(v)+1 : v>0 ? v+1 : exp(v)
    return v > 0.0f ? v + 1.0f : __expf(v);
}

// ---------------------------------------------------------------------------
// Pass 1: km = elu(Wk x + bk)+1 for a 256-pixel chunk (kept in LDS),
//         S[b][k][c] += sum_px x[c][px]*km[k][px],  Z[b][k] += sum_px km[k][px]
// grid (64 chunks, B), 256 thr.
// Phase A: thread = pixel, x coalesced from global, Wk via uniform s_loads.
// Phase B: thread = (8 k's, 4 channels), x via ds_read_b128, km via uniform
//          broadcast quads. Sacc[8][4] = 32 VGPRs (no spill).
// ---------------------------------------------------------------------------
__global__ __launch_bounds__(256, 2) void k_km_S(const float* __restrict__ x,
                                                 const float* __restrict__ Wk,
                                                 const float* __restrict__ bk,
                                                 float* __restrict__ S,
                                                 float* __restrict__ Z) {
    __shared__ float xs[Cn][36];    // [c][px32] pad 36: conflict-free writes, 16B rows
    __shared__ float km[KCn][260];  // [k][px256] pad 260: 16B-aligned rows

    const int t  = threadIdx.x;
    const int b  = blockIdx.y;
    const int n0 = blockIdx.x * 256;
    const float* xb = x + (size_t)b * Cn * Nn;

    // ---- phase A: km for all 256 px of the chunk; thread = pixel n0+t ----
    float ka[KCn];
#pragma unroll
    for (int k = 0; k < KCn; ++k) ka[k] = bk[k];
    const float* xp = xb + n0 + t;
#pragma unroll 4
    for (int c = 0; c < Cn; ++c) {
        const float xv = xp[(size_t)c * Nn];       // coalesced across lanes
#pragma unroll
        for (int k = 0; k < KCn; ++k) ka[k] += Wk[k * Cn + c] * xv;  // uniform -> s_load
    }
#pragma unroll
    for (int k = 0; k < KCn; ++k) km[k][t] = elup1(ka[k]);
    __syncthreads();

    // ---- z: k = t>>3, 8 threads cover 256 px, shfl-reduce, 32 atomics ----
    {
        const int zk = t >> 3, zo = (t & 7) * 32;
        float zp = 0.f;
#pragma unroll 8
        for (int i = 0; i < 32; ++i) zp += km[zk][zo + i];
        zp += __shfl_down(zp, 4, 8);
        zp += __shfl_down(zp, 2, 8);
        zp += __shfl_down(zp, 1, 8);
        if ((t & 7) == 0) atomicAdd(&Z[b * KCn + zk], zp);
    }

    // ---- phase B: thread = (k in kh..kh+7, channels c0,+64,+128,+192) ----
    const int c0 = t & 63;
    const int kh = (t >> 6) * 8;
    float Sacc[8][4];
#pragma unroll
    for (int k = 0; k < 8; ++k)
#pragma unroll
        for (int j = 0; j < 4; ++j) Sacc[k][j] = 0.f;

    const int pld = t & 31, cld = t >> 5;
    for (int sub = 0; sub < 8; ++sub) {
        __syncthreads();               // protect xs from previous readers
        const int ns = n0 + sub * 32;
#pragma unroll 8
        for (int i = 0; i < 32; ++i) { // stage x subtile 256c x 32px
            const int c = i * 8 + cld;
            xs[c][pld] = xb[(size_t)c * Nn + ns + pld];
        }
        __syncthreads();
#pragma unroll 2
        for (int p4 = 0; p4 < 8; ++p4) {
            const float4 xq0 = *(const float4*)&xs[c0      ][p4 * 4];
            const float4 xq1 = *(const float4*)&xs[c0 +  64][p4 * 4];
            const float4 xq2 = *(const float4*)&xs[c0 + 128][p4 * 4];
            const float4 xq3 = *(const float4*)&xs[c0 + 192][p4 * 4];
#pragma unroll
            for (int k = 0; k < 8; ++k) {
                const float4 k4 = *(const float4*)&km[kh + k][sub * 32 + p4 * 4]; // bcast
                Sacc[k][0] += xq0.x*k4.x + xq0.y*k4.y + xq0.z*k4.z + xq0.w*k4.w;
                Sacc[k][1] += xq1.x*k4.x + xq1.y*k4.y + xq1.z*k4.z + xq1.w*k4.w;
                Sacc[k][2] += xq2.x*k4.x + xq2.y*k4.y + xq2.z*k4.z + xq2.w*k4.w;
                Sacc[k][3] += xq3.x*k4.x + xq3.y*k4.y + xq3.z*k4.z + xq3.w*k4.w;
            }
        }
    }
    // ---- flush partials (coalesced atomics, S layout [b][k][c]) ----
    float* Sb = S + (size_t)b * KCn * Cn;
#pragma unroll
    for (int k = 0; k < 8; ++k) {
        atomicAdd(&Sb[(kh + k) * Cn + c0      ], Sacc[k][0]);
        atomicAdd(&Sb[(kh + k) * Cn + c0 +  64], Sacc[k][1]);
        atomicAdd(&Sb[(kh + k) * Cn + c0 + 128], Sacc[k][2]);
        atomicAdd(&Sb[(kh + k) * Cn + c0 + 192], Sacc[k][3]);
    }
}

// ---------------------------------------------------------------------------
// Pass 2 (tiny): KV[b][k][vc] = bv[vc]*Z[b][k] + sum_c Wv[vc][c] * S[b][k][c]
// stored bf16. grid (16 k-slices of 2, B), 256 thr (t = vc).
// ---------------------------------------------------------------------------
__global__ __launch_bounds__(256) void k_kv(const float* __restrict__ Wv,
                                            const float* __restrict__ bv,
                                            const float* __restrict__ S,
                                            const float* __restrict__ Z,
                                            __hip_bfloat16* __restrict__ KV) {
    __shared__ float Sl[2][Cn];
    const int t  = threadIdx.x;
    const int b  = blockIdx.y;
    const int k0 = blockIdx.x * 2;
    const float* Sb = S + ((size_t)b * KCn + k0) * Cn;
    Sl[0][t] = Sb[t];
    Sl[1][t] = Sb[Cn + t];
    __syncthreads();
    const float z0 = Z[b * KCn + k0], z1 = Z[b * KCn + k0 + 1];
    const float bvv = bv[t];
    float acc0 = bvv * z0, acc1 = bvv * z1;
    const float4* Wv4 = (const float4*)(Wv + (size_t)t * Cn);
#pragma unroll 8
    for (int c4 = 0; c4 < Cn / 4; ++c4) {
        const float4 w  = Wv4[c4];
        const float4 s0 = *(const float4*)&Sl[0][c4 * 4];
        const float4 s1 = *(const float4*)&Sl[1][c4 * 4];
        acc0 += w.x * s0.x + w.y * s0.y + w.z * s0.z + w.w * s0.w;
        acc1 += w.x * s1.x + w.y * s1.y + w.z * s1.z + w.w * s1.w;
    }
    KV[((size_t)b * KCn + k0 + 0) * Cn + t] = __float2bfloat16(acc0);
    KV[((size_t)b * KCn + k0 + 1) * Cn + t] = __float2bfloat16(acc1);
}

// ---------------------------------------------------------------------------
// Pass 3: per pixel qm = elu(Wq x + bq)+1; fold r = gamma/max(qz,1e-6) into qm;
//         out[b][vc][n] = sum_k qm'[k][n]*KV[k][vc] + x[b][vc][n]
// grid (64 chunks, B), 256 thr. q-phase: thread = pixel. out-phase: 4vc x 4px.
// ---------------------------------------------------------------------------
__global__ __launch_bounds__(256) void k_out(const float* __restrict__ x,
                                             const float* __restrict__ Wq,
                                             const float* __restrict__ bq,
                                             const __hip_bfloat16* __restrict__ KV,
                                             const float* __restrict__ Z,
                                             const float* __restrict__ gamma,
                                             float* __restrict__ out) {
    __shared__ float          qml[KCn][Cn];  // [k][pixel]  32 KB
    __shared__ __hip_bfloat16 kvl[KCn][Cn];  // [k][vc]     16 KB
    const int t  = threadIdx.x;
    const int b  = blockIdx.y;
    const int n0 = blockIdx.x * 256;
    const float* xb = x + (size_t)b * Cn * Nn;

    // ---- stage KV (8192 bf16, coalesced dword copies) ----
    {
        const unsigned int* src = (const unsigned int*)(KV + (size_t)b * KCn * Cn);
        unsigned int*       dst = (unsigned int*)&kvl[0][0];
#pragma unroll
        for (int i = 0; i < 16; ++i) dst[i * 256 + t] = src[i * 256 + t];
    }

    // ---- q phase: thread = pixel n0+t ----
    float qacc[KCn];
#pragma unroll
    for (int k = 0; k < KCn; ++k) qacc[k] = 0.f;
    const float* xp = xb + n0 + t;
#pragma unroll 4
    for (int c = 0; c < Cn; ++c) {
        const float xv = xp[(size_t)c * Nn];     // coalesced across lanes
        const float* wq = Wq + c;                // uniform -> scalar loads
#pragma unroll
        for (int k = 0; k < KCn; ++k) qacc[k] += wq[k * Cn] * xv;
    }
    float qz = 0.f;
#pragma unroll
    for (int k = 0; k < KCn; ++k) {
        qacc[k] = elup1(qacc[k] + bq[k]);
        qz += qacc[k] * Z[b * KCn + k];
    }
    const float r = gamma[0] / fmaxf(qz, 1e-6f);
#pragma unroll
    for (int k = 0; k < KCn; ++k) qml[k][t] = qacc[k] * r;
    __syncthreads();

    // ---- out phase: thread = (pixel-quad pq, vc-quad group vq) ----
    const int pq = t & 63;
    const int vq = t >> 6;
#pragma unroll 1
    for (int vs = 0; vs < 16; ++vs) {
        const int vc0 = vs * 16 + vq * 4;
        float a[4][4];
#pragma unroll
        for (int i = 0; i < 4; ++i)
#pragma unroll
            for (int j = 0; j < 4; ++j) a[i][j] = 0.f;
#pragma unroll
        for (int k = 0; k < KCn; ++k) {
            const float4  q4 = *(const float4*)&qml[k][pq * 4];       // b128
            const ushort4 kh = *(const ushort4*)&kvl[k][vc0];         // b64 bcast
            const float k0f = __uint_as_float((unsigned int)kh.x << 16);
            const float k1f = __uint_as_float((unsigned int)kh.y << 16);
            const float k2f = __uint_as_float((unsigned int)kh.z << 16);
            const float k3f = __uint_as_float((unsigned int)kh.w << 16);
            a[0][0] += k0f * q4.x; a[0][1] += k0f * q4.y; a[0][2] += k0f * q4.z; a[0][3] += k0f * q4.w;
            a[1][0] += k1f * q4.x; a[1][1] += k1f * q4.y; a[1][2] += k1f * q4.z; a[1][3] += k1f * q4.w;
            a[2][0] += k2f * q4.x; a[2][1] += k2f * q4.y; a[2][2] += k2f * q4.z; a[2][3] += k2f * q4.w;
            a[3][0] += k3f * q4.x; a[3][1] += k3f * q4.y; a[3][2] += k3f * q4.z; a[3][3] += k3f * q4.w;
        }
#pragma unroll
        for (int i = 0; i < 4; ++i) {
            const int vc = vc0 + i;
            const float4 xv4 = *(const float4*)(xb + (size_t)vc * Nn + n0 + pq * 4);
            float4 o;
            o.x = a[i][0] + xv4.x;
            o.y = a[i][1] + xv4.y;
            o.z = a[i][2] + xv4.z;
            o.w = a[i][3] + xv4.w;
            *(float4*)(out + ((size_t)b * Cn + vc) * Nn + n0 + pq * 4) = o;
        }
    }
}

// ---------------------------------------------------------------------------
extern "C" void kernel_launch(void* const* d_in, const int* in_sizes, int n_in,
                              void* d_out, int out_size, void* d_ws, size_t ws_size,
                              hipStream_t stream) {
    const float* x     = (const float*)d_in[0];
    const float* Wq    = (const float*)d_in[1];
    const float* bq    = (const float*)d_in[2];
    const float* Wk    = (const float*)d_in[3];
    const float* bk    = (const float*)d_in[4];
    const float* Wv    = (const float*)d_in[5];
    const float* bv    = (const float*)d_in[6];
    const float* gamma = (const float*)d_in[7];
    float* out = (float*)d_out;

    // workspace layout: S fp32 [B][KC][C] | Z fp32 [B][KC] | KV bf16 [B][KC][C]
    float* S = (float*)d_ws;
    float* Z = S + (size_t)Bn * KCn * Cn;
    __hip_bfloat16* KV = (__hip_bfloat16*)(Z + (size_t)Bn * KCn);

    hipMemsetAsync(d_ws, 0, ((size_t)Bn * KCn * Cn + Bn * KCn) * sizeof(float), stream);
    k_km_S<<<dim3(64, Bn), 256, 0, stream>>>(x, Wk, bk, S, Z);
    k_kv  <<<dim3(16, Bn), 256, 0, stream>>>(Wv, bv, S, Z, KV);
    k_out <<<dim3(64, Bn), 256, 0, stream>>>(x, Wq, bq, KV, Z, gamma, out);
}